// Round 7
// baseline (167.437 us; speedup 1.0000x reference)
//
#include <hip/hip_runtime.h>
#include <math.h>

// ---------------------------------------------------------------------------
// LorentzSelfAttention — MI355X
//
// Degenerate-clamp simplification (verified analytically, passed R1-R6):
//   u_agg_i = C*(W_i + S_i*Q_i),  W_i = sum_j attn*dist*V_j,
//                                 S_i = sum_j attn*dist*alpha_ij
//   Y_i = mink_normalize(Q_i + u_agg_i), |time|
//   Ztan_i = dist0*C * (2*Y0, Ys),  dist0 = acosh(max(Y0,1+eps))
//
// R7: K/V stored ROW-major [j][36] with Lorentz sign folded (row[32] = -time,
// pads 0) so ip = -dot36(Q,row) -> 9 float4 loads/row instead of 66 scalar.
// Second V copy in W-order [v0, vs, 0x3] for P4. GEMMs retiled 32x64 for
// 2x block count (occupancy). All f32 (no precision change vs R6).
// ---------------------------------------------------------------------------

namespace {

constexpr int Tq = 512;
constexpr int QS = 36;            // padded row stride (Q, Ka, Va, Vw)

#define EPSF  1e-6f
#define CINV  3.16227766e7f       // 1/sqrt(1e-15)

__device__ __forceinline__ float facosh(float x) {
    // caller guarantees x >= 1+1e-6
    return __logf(x + __builtin_amdgcn_sqrtf(fmaf(x, x, -1.0f)));
}

// ---------------- Kernel 1: QKV GEMM (32x64 tile) + fused FL lift ----------
// Writes: Q  row [qs*inv x32][q0][0 0 0]
//         Ka row [ks*inv x32][-k0][0 0 0]
//         Va row [vs*inv x32][-v0][0 0 0]
//         Vw row [v0][vs*inv x32][0 0 0]
__global__ __launch_bounds__(256) void gemm_qkv_fl_kernel(
    const float* __restrict__ x,
    const float* __restrict__ Wq, const float* __restrict__ bq,
    const float* __restrict__ Wk, const float* __restrict__ bk,
    const float* __restrict__ Wv, const float* __restrict__ bv,
    float* __restrict__ Q, float* __restrict__ Ka,
    float* __restrict__ Va, float* __restrict__ Vw)
{
    __shared__ float AsT[32][36];     // k-major
    __shared__ float BsT[32][68];
    __shared__ float sT[32][65];      // epilogue z-tile

    const int n0 = blockIdx.x * 64;   // 0..704
    const int m0 = blockIdx.y * 32;   // 0..992
    const int t  = threadIdx.x;
    const int tx = t & 15, ty = t >> 4;

    float acc[2][4];
    #pragma unroll
    for (int r = 0; r < 2; ++r)
        #pragma unroll
        for (int c = 0; c < 4; ++c) acc[r][c] = 0.f;

    const int ob  = n0 + (t >> 2);    // B row this thread stages (0..767)
    const float* WselB = (ob < 256) ? Wq : (ob < 512 ? Wk : Wv);
    const int obr = ob & 255;
    const int ar  = t >> 3;           // A row 0..31
    const int ac  = (t & 7) * 4;      // 0..28
    const int bcc = (t & 3) * 8;      // 0,8,16,24

    for (int k0 = 0; k0 < 512; k0 += 32) {
        const float4 av = *reinterpret_cast<const float4*>(&x[(m0 + ar) * 512 + k0 + ac]);
        AsT[ac + 0][ar] = av.x; AsT[ac + 1][ar] = av.y;
        AsT[ac + 2][ar] = av.z; AsT[ac + 3][ar] = av.w;
        const float4 b0 = *reinterpret_cast<const float4*>(&WselB[obr * 512 + k0 + bcc]);
        const float4 b1 = *reinterpret_cast<const float4*>(&WselB[obr * 512 + k0 + bcc + 4]);
        const int bcol = t >> 2;
        BsT[bcc + 0][bcol] = b0.x; BsT[bcc + 1][bcol] = b0.y;
        BsT[bcc + 2][bcol] = b0.z; BsT[bcc + 3][bcol] = b0.w;
        BsT[bcc + 4][bcol] = b1.x; BsT[bcc + 5][bcol] = b1.y;
        BsT[bcc + 6][bcol] = b1.z; BsT[bcc + 7][bcol] = b1.w;
        __syncthreads();
        #pragma unroll
        for (int kk = 0; kk < 32; ++kk) {
            const float2 a2 = *reinterpret_cast<const float2*>(&AsT[kk][ty * 2]);
            const float4 b4 = *reinterpret_cast<const float4*>(&BsT[kk][tx * 4]);
            const float ar2[2] = {a2.x, a2.y};
            const float br4[4] = {b4.x, b4.y, b4.z, b4.w};
            #pragma unroll
            for (int r = 0; r < 2; ++r)
                #pragma unroll
                for (int c = 0; c < 4; ++c) acc[r][c] = fmaf(ar2[r], br4[c], acc[r][c]);
        }
        __syncthreads();
    }

    #pragma unroll
    for (int c = 0; c < 4; ++c) {
        const int o = n0 + tx * 4 + c;
        const float* bsel = (o < 256) ? bq : (o < 512 ? bk : bv);
        const float bias = bsel[o & 255];
        #pragma unroll
        for (int r = 0; r < 2; ++r)
            sT[ty * 2 + r][tx * 4 + c] = acc[r][c] + bias;
    }
    __syncthreads();

    if (t < 64) {
        const int m = t >> 1, half = t & 1;
        const int row = m0 + m;
        const int b = row >> 9, tt = row & 511;
        const int which = n0 >> 8;           // 0=q 1=k 2=v
        const int h = ((n0 & 255) >> 5) + half;
        const int bh = b * 8 + h;

        float zv[32];
        float s2 = 0.f;
        #pragma unroll
        for (int k = 0; k < 32; ++k) { zv[k] = sT[m][half * 32 + k]; s2 = fmaf(zv[k], zv[k], s2); }
        const float rr = __builtin_amdgcn_sqrtf(s2);
        const float rs = fminf(fmaxf(rr, 1e-12f), 18.0f);
        const float e  = __expf(rs);
        const float ei = __builtin_amdgcn_rcpf(e);
        const float ch = 0.5f * (e + ei);
        float sc = 0.5f * (e - ei) / rs;
        if (rs < 1e-3f) sc = fmaf(rs * rs, 1.0f / 6.0f, 1.0f);
        float y0 = ch;
        float ys[32];
        float mink = -y0 * y0;
        #pragma unroll
        for (int k = 0; k < 32; ++k) { ys[k] = sc * zv[k]; mink = fmaf(ys[k], ys[k], mink); }
        const float inv = __builtin_amdgcn_rsqf(fmaxf(fabsf(mink), 1e-15f));
        y0 = fabsf(y0 * inv);

        const long base = (long)(bh * Tq + tt) * QS;
        if (which == 0) {
            float* qp = Q + base;
            #pragma unroll
            for (int k = 0; k < 32; ++k) qp[k] = ys[k] * inv;
            qp[32] = y0; qp[33] = 0.f; qp[34] = 0.f; qp[35] = 0.f;
        } else if (which == 1) {
            float* kp = Ka + base;
            #pragma unroll
            for (int k = 0; k < 32; ++k) kp[k] = ys[k] * inv;
            kp[32] = -y0; kp[33] = 0.f; kp[34] = 0.f; kp[35] = 0.f;
        } else {
            float* vp = Va + base;
            float* wp = Vw + base;
            wp[0] = y0;
            #pragma unroll
            for (int k = 0; k < 32; ++k) {
                const float v = ys[k] * inv;
                vp[k] = v; wp[1 + k] = v;
            }
            vp[32] = -y0; vp[33] = 0.f; vp[34] = 0.f; vp[35] = 0.f;
            wp[33] = 0.f; wp[34] = 0.f; wp[35] = 0.f;
        }
    }
}

// ---------------- Kernel 2: attention + Karcher step + origin log ----------
// 256 threads, 8 rows/block, 2 columns/thread, grid (64, 16).
// ip/alpha = -dot36(Qrow, K/Vrow) via 9 float4 row loads.
__global__ __launch_bounds__(256) void attn_kernel(
    const float* __restrict__ Q, const float* __restrict__ Ka,
    const float* __restrict__ Va, const float* __restrict__ Vw,
    float* __restrict__ Ztan)
{
    __shared__ float sQ[8][36];
    __shared__ float sBig[8 * 512];   // p matrix; P4 partials alias
    __shared__ float sSe[8][4];
    __shared__ float sSa[8][4];
    __shared__ float sW[8][33];

    float (*sP)[512] = reinterpret_cast<float(*)[512]>(sBig);
    float (*part)[8][36] = reinterpret_cast<float(*)[8][36]>(sBig);

    const int bh = blockIdx.y;
    const int i0 = blockIdx.x * 8;
    const int t  = threadIdx.x;       // 0..255
    const int lane = t & 63, wv = t >> 6;

    const float* Qb  = Q  + (bh * Tq + i0) * QS;
    const float* Kab = Ka + bh * Tq * QS;
    const float* Vab = Va + bh * Tq * QS;
    const float* Vwb = Vw + bh * Tq * QS;

    for (int idx = t; idx < 8 * QS; idx += 256)
        sQ[idx / QS][idx % QS] = Qb[idx];
    __syncthreads();

    float se[8], sa[8];
    #pragma unroll
    for (int i = 0; i < 8; ++i) { se[i] = 0.f; sa[i] = 0.f; }

    // ---- P1: p = exp(-d^2)*dd into LDS; row sums of e and p*al in regs ----
    #pragma unroll 1
    for (int cc = 0; cc < 2; ++cc) {
        const int j = (cc << 8) + t;
        float dK[8];
        {
            float4 kr[9];
            #pragma unroll
            for (int c = 0; c < 9; ++c)
                kr[c] = *reinterpret_cast<const float4*>(&Kab[j * QS + c * 4]);
            #pragma unroll
            for (int i = 0; i < 8; ++i) {
                float d0 = 0.f, d1 = 0.f, d2 = 0.f, d3 = 0.f;
                #pragma unroll
                for (int c = 0; c < 9; ++c) {
                    const float4 q4 = *reinterpret_cast<const float4*>(&sQ[i][c * 4]);
                    d0 = fmaf(q4.x, kr[c].x, d0);
                    d1 = fmaf(q4.y, kr[c].y, d1);
                    d2 = fmaf(q4.z, kr[c].z, d2);
                    d3 = fmaf(q4.w, kr[c].w, d3);
                }
                const float ip = -((d0 + d1) + (d2 + d3));
                dK[i] = facosh(fmaxf(ip, 1.0f + EPSF));
            }
        }
        {
            float4 vr[9];
            #pragma unroll
            for (int c = 0; c < 9; ++c)
                vr[c] = *reinterpret_cast<const float4*>(&Vab[j * QS + c * 4]);
            #pragma unroll
            for (int i = 0; i < 8; ++i) {
                float d0 = 0.f, d1 = 0.f, d2 = 0.f, d3 = 0.f;
                #pragma unroll
                for (int c = 0; c < 9; ++c) {
                    const float4 q4 = *reinterpret_cast<const float4*>(&sQ[i][c * 4]);
                    d0 = fmaf(q4.x, vr[c].x, d0);
                    d1 = fmaf(q4.y, vr[c].y, d1);
                    d2 = fmaf(q4.z, vr[c].z, d2);
                    d3 = fmaf(q4.w, vr[c].w, d3);
                }
                const float al = fmaxf(-((d0 + d1) + (d2 + d3)), 1.0f + EPSF);
                const float dd = facosh(al);
                const float e  = __expf(-dK[i] * dK[i]);
                const float p  = e * dd;
                sP[i][j] = p;
                se[i] += e;
                sa[i]  = fmaf(p, al, sa[i]);
            }
        }
    }
    #pragma unroll
    for (int i = 0; i < 8; ++i) {
        float a = se[i], b = sa[i];
        #pragma unroll
        for (int off = 32; off > 0; off >>= 1) {
            a += __shfl_xor(a, off, 64);
            b += __shfl_xor(b, off, 64);
        }
        if (lane == 0) { sSe[i][wv] = a; sSa[i][wv] = b; }
    }
    __syncthreads();

    // ---- P4: Wraw[i][a] = sum_j p_ij * Vw[j][a] ---------------------------
    // 8 half-wave groups: g = ag*2 + rg; rows rg*4..+3, a = ag*8..+8 (9 wide).
    {
        const int jl = t & 31, g = t >> 5;
        const int rg = g & 1, ag = g >> 1;
        const int abase = ag * 8;         // 0,8,16,24; +8 = 32 in range
        const int ibase = rg * 4;
        float acc[4][9];
        #pragma unroll
        for (int il = 0; il < 4; ++il)
            #pragma unroll
            for (int al = 0; al < 9; ++al) acc[il][al] = 0.f;

        #pragma unroll 1
        for (int jt = 0; jt < 16; ++jt) {
            const int j = jt * 32 + jl;
            const float4 va = *reinterpret_cast<const float4*>(&Vwb[j * QS + abase]);
            const float4 vb = *reinterpret_cast<const float4*>(&Vwb[j * QS + abase + 4]);
            const float  vc = Vwb[j * QS + abase + 8];
            #pragma unroll
            for (int il = 0; il < 4; ++il) {
                const float w = sP[ibase + il][j];
                acc[il][0] = fmaf(w, va.x, acc[il][0]);
                acc[il][1] = fmaf(w, va.y, acc[il][1]);
                acc[il][2] = fmaf(w, va.z, acc[il][2]);
                acc[il][3] = fmaf(w, va.w, acc[il][3]);
                acc[il][4] = fmaf(w, vb.x, acc[il][4]);
                acc[il][5] = fmaf(w, vb.y, acc[il][5]);
                acc[il][6] = fmaf(w, vb.z, acc[il][6]);
                acc[il][7] = fmaf(w, vb.w, acc[il][7]);
                acc[il][8] = fmaf(w, vc,   acc[il][8]);
            }
        }
        #pragma unroll
        for (int il = 0; il < 4; ++il)
            #pragma unroll
            for (int al = 0; al < 9; ++al) {
                float v = acc[il][al];
                v += __shfl_xor(v, 1, 64);
                v += __shfl_xor(v, 2, 64);
                acc[il][al] = v;
            }
        __syncthreads();   // all sP reads complete before part overwrites
        if ((jl & 3) == 0) {
            const int sub = jl >> 2;
            #pragma unroll
            for (int il = 0; il < 4; ++il)
                #pragma unroll
                for (int al = 0; al < 9; ++al)
                    part[g][sub][il * 9 + al] = acc[il][al];
        }
    }
    __syncthreads();

    // ---- stage 2: fold 8 partials per (i,a) -------------------------------
    for (int task = t; task < 8 * 33; task += 256) {
        const int i = task / 33, a = task - i * 33;
        int ag2 = a >> 3; if (ag2 > 3) ag2 = 3;
        const int al = a - ag2 * 8;
        const int g2 = ag2 * 2 + (i >> 2);
        const int idx = (i & 3) * 9 + al;
        float s = 0.f;
        #pragma unroll
        for (int sub = 0; sub < 8; ++sub) s += part[g2][sub][idx];
        sW[i][a] = s;
    }
    __syncthreads();

    // ---- P5: normalize + degenerate exp_map + project + origin log --------
    if (t < 8) {
        const int i = t;
        const float seT = sSe[i][0] + sSe[i][1] + sSe[i][2] + sSe[i][3];
        const float saT = sSa[i][0] + sSa[i][1] + sSa[i][2] + sSa[i][3];
        const float sInv = __builtin_amdgcn_rcpf(seT);
        const float cs = CINV * sInv;     // C * (1/sum_e)
        const float q0 = sQ[i][32];
        const float y0 = fmaf(cs, fmaf(saT, q0, sW[i][0]), q0);
        float mink = -y0 * y0;
        float yv[32];
        #pragma unroll
        for (int a = 1; a < 33; ++a) {
            const float qa = sQ[i][a - 1];
            const float ya = fmaf(cs, fmaf(saT, qa, sW[i][a]), qa);
            yv[a - 1] = ya;
            mink = fmaf(ya, ya, mink);
        }
        const float inv = __builtin_amdgcn_rsqf(fmaxf(fabsf(mink), 1e-15f));
        const float Y0 = fabsf(y0 * inv);
        const float dist0 = facosh(fmaxf(Y0, 1.0f + EPSF));
        const float coef = dist0 * CINV;
        const int b = bh >> 3, h = bh & 7;
        float* zp = Ztan + ((b * Tq + (i0 + i)) * 264) + h * 33;
        zp[0] = coef * (2.0f * Y0);
        #pragma unroll
        for (int a = 1; a < 33; ++a) zp[a] = coef * (yv[a - 1] * inv);
    }
}

// ---------------- Kernel 3: Z = Ztan(1024x264) @ Wo^T + bo (32x64 tile) ----
__global__ __launch_bounds__(256) void out_gemm_kernel(
    const float* __restrict__ Ztan, const float* __restrict__ Wo,
    const float* __restrict__ bo, float* __restrict__ out)
{
    __shared__ float AsT[8][36];
    __shared__ float BsT[8][68];
    const int n0 = blockIdx.x * 64;
    const int m0 = blockIdx.y * 32;
    const int t  = threadIdx.x;
    const int tx = t & 15, ty = t >> 4;
    const int ar = t >> 3, ac = t & 7;       // A: 32 rows x 8 k
    const int br = t >> 2, bc2 = (t & 3) * 2; // B: 64 rows x 8 k (float2)

    float acc[2][4];
    #pragma unroll
    for (int r = 0; r < 2; ++r)
        #pragma unroll
        for (int c = 0; c < 4; ++c) acc[r][c] = 0.f;

    for (int k0 = 0; k0 < 264; k0 += 8) {
        AsT[ac][ar] = Ztan[(m0 + ar) * 264 + k0 + ac];
        const float2 b2 = *reinterpret_cast<const float2*>(&Wo[(n0 + br) * 264 + k0 + bc2]);
        BsT[bc2][br] = b2.x; BsT[bc2 + 1][br] = b2.y;
        __syncthreads();
        #pragma unroll
        for (int kk = 0; kk < 8; ++kk) {
            const float2 a2 = *reinterpret_cast<const float2*>(&AsT[kk][ty * 2]);
            const float4 b4 = *reinterpret_cast<const float4*>(&BsT[kk][tx * 4]);
            const float ar2[2] = {a2.x, a2.y};
            const float br4[4] = {b4.x, b4.y, b4.z, b4.w};
            #pragma unroll
            for (int r = 0; r < 2; ++r)
                #pragma unroll
                for (int c = 0; c < 4; ++c) acc[r][c] = fmaf(ar2[r], br4[c], acc[r][c]);
        }
        __syncthreads();
    }
    #pragma unroll
    for (int c = 0; c < 4; ++c) {
        const int o = n0 + tx * 4 + c;
        const float bias = bo[o];
        #pragma unroll
        for (int r = 0; r < 2; ++r)
            out[(m0 + ty * 2 + r) * 512 + o] = acc[r][c] + bias;
    }
}

} // namespace

// ---------------------------------------------------------------------------
extern "C" void kernel_launch(void* const* d_in, const int* in_sizes, int n_in,
                              void* d_out, int out_size, void* d_ws, size_t ws_size,
                              hipStream_t stream)
{
    const float* x  = (const float*)d_in[0];
    const float* Wq = (const float*)d_in[1];
    const float* bq = (const float*)d_in[2];
    const float* Wk = (const float*)d_in[3];
    const float* bk = (const float*)d_in[4];
    const float* Wv = (const float*)d_in[5];
    const float* bv = (const float*)d_in[6];
    const float* Wo = (const float*)d_in[7];
    const float* bo = (const float*)d_in[8];
    float* out = (float*)d_out;

    float* ws  = (float*)d_ws;
    float* Qw  = ws;                   // 16*512*36 = 294912 each
    float* Kap = ws + 294912;
    float* Vap = ws + 2 * 294912;
    float* Vwp = ws + 3 * 294912;
    float* Zt  = ws + 4 * 294912;      // 1024*264 = 270336

    gemm_qkv_fl_kernel<<<dim3(12, 32), 256, 0, stream>>>(x, Wq, bq, Wk, bk, Wv, bv,
                                                         Qw, Kap, Vap, Vwp);
    attn_kernel<<<dim3(64, 16), 256, 0, stream>>>(Qw, Kap, Vap, Vwp, Zt);
    out_gemm_kernel<<<dim3(8, 32), 256, 0, stream>>>(Zt, Wo, bo, out);
}

// Round 8
// 79.913 us; speedup vs baseline: 2.0952x; 2.0952x over previous
//
#include <hip/hip_runtime.h>
#include <math.h>

// ---------------------------------------------------------------------------
// LorentzSelfAttention — MI355X
//
// Degenerate-clamp simplification (verified analytically, passed R1-R7):
//   u_agg_i = C*(W_i + S_i*Q_i),  W_i = sum_j attn*dist*V_j,
//                                 S_i = sum_j attn*dist*alpha_ij
//   Y_i = mink_normalize(Q_i + u_agg_i), |time|
//   Ztan_i = dist0*C * (2*Y0, Ys),  dist0 = acosh(max(Y0,1+eps))
//
// R8: attn restored to R6 (dim-major K/V, coalesced — R7's row-major had 8x
// HBM overfetch + VGPR=256). QKV GEMM split-K x2 (768 blocks, 3/CU) with a
// reduce+bias+FL pass. out_gemm retiled 32x32 (512 blocks). All f32.
// ---------------------------------------------------------------------------

namespace {

constexpr int Tq = 512;
constexpr int QS = 36;            // padded Q row stride
constexpr int ZPHALF = 786432;    // 1024*768

#define EPSF  1e-6f
#define CINV  3.16227766e7f       // 1/sqrt(1e-15)

__device__ __forceinline__ float facosh(float x) {
    // caller guarantees x >= 1+1e-6
    return __logf(x + __builtin_amdgcn_sqrtf(fmaf(x, x, -1.0f)));
}

// ---------------- Kernel 1: QKV GEMM, split-K x2, 32x64 tiles --------------
__global__ __launch_bounds__(256) void gemm_qkv_split_kernel(
    const float* __restrict__ x,
    const float* __restrict__ Wq, const float* __restrict__ Wk,
    const float* __restrict__ Wv, float* __restrict__ zpart)
{
    __shared__ float AsT[32][36];     // k-major
    __shared__ float BsT[32][68];

    const int n0 = blockIdx.x * 64;   // 0..704
    const int m0 = blockIdx.y * 32;   // 0..992
    const int kz = blockIdx.z;        // 0/1
    const int t  = threadIdx.x;
    const int tx = t & 15, ty = t >> 4;

    float acc[2][4];
    #pragma unroll
    for (int r = 0; r < 2; ++r)
        #pragma unroll
        for (int c = 0; c < 4; ++c) acc[r][c] = 0.f;

    const int ob  = n0 + (t >> 2);    // B row staged by this thread
    const float* WselB = (ob < 256) ? Wq : (ob < 512 ? Wk : Wv);
    const int obr = ob & 255;
    const int ar  = t >> 3;           // A row 0..31
    const int ac  = (t & 7) * 4;      // k 0..28
    const int bcc = (t & 3) * 8;      // k 0,8,16,24
    const int bcol = t >> 2;          // 0..63

    const int kbeg = kz * 256;
    for (int k0 = kbeg; k0 < kbeg + 256; k0 += 32) {
        const float4 av = *reinterpret_cast<const float4*>(&x[(m0 + ar) * 512 + k0 + ac]);
        AsT[ac + 0][ar] = av.x; AsT[ac + 1][ar] = av.y;
        AsT[ac + 2][ar] = av.z; AsT[ac + 3][ar] = av.w;
        const float4 b0 = *reinterpret_cast<const float4*>(&WselB[obr * 512 + k0 + bcc]);
        const float4 b1 = *reinterpret_cast<const float4*>(&WselB[obr * 512 + k0 + bcc + 4]);
        BsT[bcc + 0][bcol] = b0.x; BsT[bcc + 1][bcol] = b0.y;
        BsT[bcc + 2][bcol] = b0.z; BsT[bcc + 3][bcol] = b0.w;
        BsT[bcc + 4][bcol] = b1.x; BsT[bcc + 5][bcol] = b1.y;
        BsT[bcc + 6][bcol] = b1.z; BsT[bcc + 7][bcol] = b1.w;
        __syncthreads();
        #pragma unroll
        for (int kk = 0; kk < 32; ++kk) {
            const float2 a2 = *reinterpret_cast<const float2*>(&AsT[kk][ty * 2]);
            const float4 b4 = *reinterpret_cast<const float4*>(&BsT[kk][tx * 4]);
            const float ar2[2] = {a2.x, a2.y};
            const float br4[4] = {b4.x, b4.y, b4.z, b4.w};
            #pragma unroll
            for (int r = 0; r < 2; ++r)
                #pragma unroll
                for (int c = 0; c < 4; ++c) acc[r][c] = fmaf(ar2[r], br4[c], acc[r][c]);
        }
        __syncthreads();
    }
    float* zp = zpart + kz * ZPHALF + (m0 + ty * 2) * 768 + n0 + tx * 4;
    #pragma unroll
    for (int r = 0; r < 2; ++r) {
        float4 o; o.x = acc[r][0]; o.y = acc[r][1]; o.z = acc[r][2]; o.w = acc[r][3];
        *reinterpret_cast<float4*>(zp + r * 768) = o;
    }
}

// ---------------- Kernel 2: reduce halves + bias + FL lift -----------------
// unit u = (which, bh, tt). Q padded [bh][tt][36]; K,V dim-major [bh][a][Tq].
__global__ __launch_bounds__(256) void reduce_fl_kernel(
    const float* __restrict__ zpart,
    const float* __restrict__ bq, const float* __restrict__ bk,
    const float* __restrict__ bv,
    float* __restrict__ Q, float* __restrict__ K, float* __restrict__ V)
{
    const int u = blockIdx.x * 256 + threadIdx.x;   // < 24576
    const int tt = u & 511;
    const int rest = u >> 9;          // 0..47
    const int bh = rest & 15;
    const int which = rest >> 4;      // 0=q 1=k 2=v
    const int b = bh >> 3, h = bh & 7;
    const int row = b * 512 + tt;
    const int col = which * 256 + h * 32;
    const float* z0 = zpart + row * 768 + col;
    const float* z1 = zpart + ZPHALF + row * 768 + col;
    const float* bsel = (which == 0) ? bq : (which == 1 ? bk : bv);

    float zv[32];
    float s2 = 0.f;
    #pragma unroll
    for (int c = 0; c < 8; ++c) {
        const float4 a = *reinterpret_cast<const float4*>(&z0[c * 4]);
        const float4 d = *reinterpret_cast<const float4*>(&z1[c * 4]);
        const float4 bb = *reinterpret_cast<const float4*>(&bsel[h * 32 + c * 4]);
        zv[c*4+0] = a.x + d.x + bb.x; zv[c*4+1] = a.y + d.y + bb.y;
        zv[c*4+2] = a.z + d.z + bb.z; zv[c*4+3] = a.w + d.w + bb.w;
    }
    #pragma unroll
    for (int k = 0; k < 32; ++k) s2 = fmaf(zv[k], zv[k], s2);

    const float rr = __builtin_amdgcn_sqrtf(s2);
    const float rs = fminf(fmaxf(rr, 1e-12f), 18.0f);
    const float e  = __expf(rs);
    const float ei = __builtin_amdgcn_rcpf(e);
    const float ch = 0.5f * (e + ei);
    float sc = 0.5f * (e - ei) / rs;
    if (rs < 1e-3f) sc = fmaf(rs * rs, 1.0f / 6.0f, 1.0f);
    float y0 = ch;
    float ys[32];
    float mink = -y0 * y0;
    #pragma unroll
    for (int k = 0; k < 32; ++k) { ys[k] = sc * zv[k]; mink = fmaf(ys[k], ys[k], mink); }
    const float inv = __builtin_amdgcn_rsqf(fmaxf(fabsf(mink), 1e-15f));
    y0 = fabsf(y0 * inv);

    if (which == 0) {
        float* qp = Q + (bh * Tq + tt) * QS;
        #pragma unroll
        for (int k = 0; k < 32; ++k) qp[k] = ys[k] * inv;
        qp[32] = y0; qp[33] = 0.f; qp[34] = 0.f; qp[35] = 0.f;
    } else {
        float* p = ((which == 1) ? K : V) + bh * 33 * Tq + tt;
        p[0] = y0;
        #pragma unroll
        for (int k = 0; k < 32; ++k) p[(k + 1) * Tq] = ys[k] * inv;
    }
}

// ---------------- Kernel 3: attention (R6 verbatim) ------------------------
// 256 threads, 8 rows/block, 2 columns/thread, grid (64, 16).
__global__ __launch_bounds__(256) void attn_kernel(
    const float* __restrict__ Q, const float* __restrict__ K,
    const float* __restrict__ V, float* __restrict__ Ztan)
{
    __shared__ float sQ[8][36];       // [0..31]=spatial, [32]=time, 33-35 pad
    __shared__ float sBig[8 * 512];   // p matrix; P4 partials alias front
    __shared__ float sSe[8][4];       // per-wave sum_e partials
    __shared__ float sSa[8][4];       // per-wave sum_(p*al) partials
    __shared__ float sW[8][33];

    float (*sP)[512] = reinterpret_cast<float(*)[512]>(sBig);
    float (*part)[8][36] = reinterpret_cast<float(*)[8][36]>(sBig); // [g][sub][36]

    const int bh = blockIdx.y;
    const int i0 = blockIdx.x * 8;
    const int t  = threadIdx.x;       // 0..255
    const int lane = t & 63, wv = t >> 6;

    const float* Qb = Q + (bh * Tq + i0) * QS;
    const float* Kb = K + bh * 33 * Tq;
    const float* Vb = V + bh * 33 * Tq;

    for (int idx = t; idx < 8 * QS; idx += 256)
        sQ[idx / QS][idx % QS] = Qb[idx];
    __syncthreads();

    // ---- P1: p = exp(-d^2)*dd into LDS; row sums of e and p*al in regs ----
    float se[8], sa[8];
    #pragma unroll
    for (int i = 0; i < 8; ++i) { se[i] = 0.f; sa[i] = 0.f; }

    #pragma unroll 1
    for (int cc = 0; cc < 2; ++cc) {
        const int j = (cc << 8) + t;
        float aK[8], aV[8];
        #pragma unroll
        for (int i = 0; i < 8; ++i) { aK[i] = 0.f; aV[i] = 0.f; }
        #pragma unroll 2
        for (int ch = 0; ch < 4; ++ch) {
            float ks[8], vs[8];
            #pragma unroll
            for (int k = 0; k < 8; ++k) {
                ks[k] = Kb[(ch * 8 + k + 1) * Tq + j];
                vs[k] = Vb[(ch * 8 + k + 1) * Tq + j];
            }
            #pragma unroll
            for (int i = 0; i < 8; ++i) {
                const float4 qa = *reinterpret_cast<const float4*>(&sQ[i][ch * 8]);
                const float4 qb = *reinterpret_cast<const float4*>(&sQ[i][ch * 8 + 4]);
                float sK = aK[i], sV = aV[i];
                sK = fmaf(qa.x, ks[0], sK); sK = fmaf(qa.y, ks[1], sK);
                sK = fmaf(qa.z, ks[2], sK); sK = fmaf(qa.w, ks[3], sK);
                sK = fmaf(qb.x, ks[4], sK); sK = fmaf(qb.y, ks[5], sK);
                sK = fmaf(qb.z, ks[6], sK); sK = fmaf(qb.w, ks[7], sK);
                sV = fmaf(qa.x, vs[0], sV); sV = fmaf(qa.y, vs[1], sV);
                sV = fmaf(qa.z, vs[2], sV); sV = fmaf(qa.w, vs[3], sV);
                sV = fmaf(qb.x, vs[4], sV); sV = fmaf(qb.y, vs[5], sV);
                sV = fmaf(qb.z, vs[6], sV); sV = fmaf(qb.w, vs[7], sV);
                aK[i] = sK; aV[i] = sV;
            }
        }
        const float k0v = Kb[j], v0v = Vb[j];
        #pragma unroll
        for (int i = 0; i < 8; ++i) {
            const float q0 = sQ[i][32];
            const float ipK = fmaf(q0, k0v, -aK[i]);
            const float d   = facosh(fmaxf(ipK, 1.0f + EPSF));
            const float al  = fmaxf(fmaf(q0, v0v, -aV[i]), 1.0f + EPSF);
            const float dd  = facosh(al);
            const float e   = __expf(-d * d);
            const float p   = e * dd;
            sP[i][j] = p;
            se[i] += e;
            sa[i]  = fmaf(p, al, sa[i]);
        }
    }
    #pragma unroll
    for (int i = 0; i < 8; ++i) {
        float a = se[i], b = sa[i];
        #pragma unroll
        for (int off = 32; off > 0; off >>= 1) {
            a += __shfl_xor(a, off, 64);
            b += __shfl_xor(b, off, 64);
        }
        if (lane == 0) { sSe[i][wv] = a; sSa[i][wv] = b; }
    }
    __syncthreads();

    // ---- P4: Wraw[i][a] = sum_j p_ij * V[a][j] ----------------------------
    {
        const int jl = t & 31, g = t >> 5;
        const int rg = g & 1, ag = g >> 1;
        const int abase = ag * 8;         // 0,8,16,24; +8 = 32 in range
        const int ibase = rg * 4;
        float acc[4][9];
        #pragma unroll
        for (int il = 0; il < 4; ++il)
            #pragma unroll
            for (int al = 0; al < 9; ++al) acc[il][al] = 0.f;

        #pragma unroll 1
        for (int it = 0; it < 8; ++it) {
            const int jb = it * 64 + jl * 2;
            float2 v2[9];
            #pragma unroll
            for (int al = 0; al < 9; ++al)
                v2[al] = *reinterpret_cast<const float2*>(&Vb[(abase + al) * Tq + jb]);
            #pragma unroll
            for (int il = 0; il < 4; ++il) {
                const float2 w2 = *reinterpret_cast<const float2*>(&sP[ibase + il][jb]);
                #pragma unroll
                for (int al = 0; al < 9; ++al)
                    acc[il][al] = fmaf(w2.y, v2[al].y, fmaf(w2.x, v2[al].x, acc[il][al]));
            }
        }
        #pragma unroll
        for (int il = 0; il < 4; ++il)
            #pragma unroll
            for (int al = 0; al < 9; ++al) {
                float v = acc[il][al];
                v += __shfl_xor(v, 1, 64);
                v += __shfl_xor(v, 2, 64);
                acc[il][al] = v;
            }
        __syncthreads();   // all sP reads complete before part overwrites
        if ((jl & 3) == 0) {
            const int sub = jl >> 2;
            #pragma unroll
            for (int il = 0; il < 4; ++il)
                #pragma unroll
                for (int al = 0; al < 9; ++al)
                    part[g][sub][il * 9 + al] = acc[il][al];
        }
    }
    __syncthreads();

    // ---- stage 2: fold 8 partials per (i,a) -------------------------------
    for (int task = t; task < 8 * 33; task += 256) {
        const int i = task / 33, a = task - i * 33;
        int ag2 = a >> 3; if (ag2 > 3) ag2 = 3;
        const int al = a - ag2 * 8;
        const int g2 = ag2 * 2 + (i >> 2);
        const int idx = (i & 3) * 9 + al;
        float s = 0.f;
        #pragma unroll
        for (int sub = 0; sub < 8; ++sub) s += part[g2][sub][idx];
        sW[i][a] = s;
    }
    __syncthreads();

    // ---- P5: normalize + degenerate exp_map + project + origin log --------
    if (t < 8) {
        const int i = t;
        const float seT = sSe[i][0] + sSe[i][1] + sSe[i][2] + sSe[i][3];
        const float saT = sSa[i][0] + sSa[i][1] + sSa[i][2] + sSa[i][3];
        const float sInv = __builtin_amdgcn_rcpf(seT);
        const float cs = CINV * sInv;     // C * (1/sum_e)
        const float q0 = sQ[i][32];
        const float y0 = fmaf(cs, fmaf(saT, q0, sW[i][0]), q0);
        float mink = -y0 * y0;
        float yv[32];
        #pragma unroll
        for (int a = 1; a < 33; ++a) {
            const float qa = sQ[i][a - 1];
            const float ya = fmaf(cs, fmaf(saT, qa, sW[i][a]), qa);
            yv[a - 1] = ya;
            mink = fmaf(ya, ya, mink);
        }
        const float inv = __builtin_amdgcn_rsqf(fmaxf(fabsf(mink), 1e-15f));
        const float Y0 = fabsf(y0 * inv);
        const float dist0 = facosh(fmaxf(Y0, 1.0f + EPSF));
        const float coef = dist0 * CINV;
        const int b = bh >> 3, h = bh & 7;
        float* zp = Ztan + ((b * Tq + (i0 + i)) * 264) + h * 33;
        zp[0] = coef * (2.0f * Y0);
        #pragma unroll
        for (int a = 1; a < 33; ++a) zp[a] = coef * (yv[a - 1] * inv);
    }
}

// ---------------- Kernel 4: Z = Ztan(1024x264) @ Wo^T + bo, 32x32 tiles ----
__global__ __launch_bounds__(256) void out_gemm_kernel(
    const float* __restrict__ Ztan, const float* __restrict__ Wo,
    const float* __restrict__ bo, float* __restrict__ out)
{
    __shared__ float AsT[8][36];
    __shared__ float BsT[8][36];
    const int n0 = blockIdx.x * 32;
    const int m0 = blockIdx.y * 32;
    const int t  = threadIdx.x;
    const int tx = t & 15, ty = t >> 4;
    const int ar = t >> 3, ac = t & 7;   // one element each

    float acc[2][2];
    acc[0][0] = acc[0][1] = acc[1][0] = acc[1][1] = 0.f;

    for (int k0 = 0; k0 < 264; k0 += 8) {
        AsT[ac][ar] = Ztan[(m0 + ar) * 264 + k0 + ac];
        BsT[ac][ar] = Wo[(n0 + ar) * 264 + k0 + ac];
        __syncthreads();
        #pragma unroll
        for (int kk = 0; kk < 8; ++kk) {
            const float2 a2 = *reinterpret_cast<const float2*>(&AsT[kk][ty * 2]);
            const float2 b2 = *reinterpret_cast<const float2*>(&BsT[kk][tx * 2]);
            acc[0][0] = fmaf(a2.x, b2.x, acc[0][0]);
            acc[0][1] = fmaf(a2.x, b2.y, acc[0][1]);
            acc[1][0] = fmaf(a2.y, b2.x, acc[1][0]);
            acc[1][1] = fmaf(a2.y, b2.y, acc[1][1]);
        }
        __syncthreads();
    }
    #pragma unroll
    for (int c = 0; c < 2; ++c) {
        const int o = n0 + tx * 2 + c;
        const float bias = bo[o];
        #pragma unroll
        for (int r = 0; r < 2; ++r)
            out[(m0 + ty * 2 + r) * 512 + o] = acc[r][c] + bias;
    }
}

} // namespace

// ---------------------------------------------------------------------------
extern "C" void kernel_launch(void* const* d_in, const int* in_sizes, int n_in,
                              void* d_out, int out_size, void* d_ws, size_t ws_size,
                              hipStream_t stream)
{
    const float* x  = (const float*)d_in[0];
    const float* Wq = (const float*)d_in[1];
    const float* bq = (const float*)d_in[2];
    const float* Wk = (const float*)d_in[3];
    const float* bk = (const float*)d_in[4];
    const float* Wv = (const float*)d_in[5];
    const float* bv = (const float*)d_in[6];
    const float* Wo = (const float*)d_in[7];
    const float* bo = (const float*)d_in[8];
    float* out = (float*)d_out;

    float* ws  = (float*)d_ws;
    float* Qw  = ws;                          // 294912
    float* Kw  = Qw + 294912;                 // 272384 (33 rows + pad)
    float* Vw  = Kw + 272384;                 // 272384
    float* Zt  = Vw + 272384;                 // 270336
    float* Zp  = Zt + 270336;                 // 2 * 786432

    gemm_qkv_split_kernel<<<dim3(12, 32, 2), 256, 0, stream>>>(x, Wq, Wk, Wv, Zp);
    reduce_fl_kernel<<<96, 256, 0, stream>>>(Zp, bq, bk, bv, Qw, Kw, Vw);
    attn_kernel<<<dim3(64, 16), 256, 0, stream>>>(Qw, Kw, Vw, Zt);
    out_gemm_kernel<<<dim3(16, 32), 256, 0, stream>>>(Zt, Wo, bo, out);
}